// Round 11
// baseline (105.687 us; speedup 1.0000x reference)
//
#include <hip/hip_runtime.h>

#define N 8192
#define IN_DIM 128
#define LD 32
#define NE 100000.0f
#define NP (N * LD)

typedef float v4f __attribute__((ext_vector_type(4)));
typedef short v8s __attribute__((ext_vector_type(8)));   // 8 bf16 (4 VGPRs)
typedef unsigned int u32;
typedef unsigned short u16;

// ---------------- Kernel A: column softmax (axis=0) of the 3 transforms ----
__global__ __launch_bounds__(256) void softmax_cols_k(
        const float* __restrict__ tz, const float* __restrict__ tg,
        const float* __restrict__ td, float* __restrict__ ws_t) {
    int b = blockIdx.x;
    const float* src = (b == 0) ? tz : (b == 1) ? tg : td;
    float* dst = ws_t + b * (IN_DIM * LD);
    int col = threadIdx.x >> 3, sub = threadIdx.x & 7;   // 32 cols x 8 subs
    float mx = -1e30f;
    #pragma unroll
    for (int j = 0; j < 16; ++j) mx = fmaxf(mx, src[(sub + 8 * j) * LD + col]);
    mx = fmaxf(mx, __shfl_xor(mx, 1));
    mx = fmaxf(mx, __shfl_xor(mx, 2));
    mx = fmaxf(mx, __shfl_xor(mx, 4));
    float s = 0.0f;
    #pragma unroll
    for (int j = 0; j < 16; ++j) s += __expf(src[(sub + 8 * j) * LD + col] - mx);
    s += __shfl_xor(s, 1);
    s += __shfl_xor(s, 2);
    s += __shfl_xor(s, 4);
    float inv = 1.0f / s;
    #pragma unroll
    for (int j = 0; j < 16; ++j)
        dst[(sub + 8 * j) * LD + col] = __expf(src[(sub + 8 * j) * LD + col] - mx) * inv;
}

// exact 3-way bf16 split (truncation): x = h + m + l, drop < 2^-24 rel
__device__ __forceinline__ void split3s(float x, u16* h, u16* m, u16* l) {
    u32 bh = __float_as_uint(x) & 0xFFFF0000u;
    float r = x - __uint_as_float(bh);          // exact
    u32 bm = __float_as_uint(r) & 0xFFFF0000u;
    float s = r - __uint_as_float(bm);          // exact
    *h = (u16)(bh >> 16);
    *m = (u16)(bm >> 16);
    *l = (u16)(__float_as_uint(s) >> 16);
}

// ---------------- Kernel B: decode GEMMs + c[i] + pre-split bf16 panels ----
#define ROWS_B 8
__global__ __launch_bounds__(256) void decode_k(
        const float* __restrict__ z1, const float* __restrict__ gamma,
        const float* __restrict__ z2, const float* __restrict__ delta,
        const float* __restrict__ ws_t,
        const float* __restrict__ p_bias, const float* __restrict__ p_wg,
        const float* __restrict__ p_wd,
        float* __restrict__ dec_out,   // d_out + N*N: z_dec1|z_dec2|gam|del
        float* __restrict__ ws_c,
        u16* __restrict__ pan) {       // 12 panels of [N][LD] bf16
    __shared__ float sZ[4][ROWS_B][IN_DIM];   // 16 KB
    int t = threadIdx.x;
    int row0 = blockIdx.x * ROWS_B;
    for (int i = t; i < 4 * ROWS_B * IN_DIM; i += 256) {
        int a = i >> 10;
        int rr = (i >> 7) & (ROWS_B - 1);
        int k = i & (IN_DIM - 1);
        const float* src = (a == 0) ? z1 : (a == 1) ? z2 : (a == 2) ? gamma : delta;
        (&sZ[0][0][0])[i] = src[(long long)(row0 + rr) * IN_DIM + k];
    }
    __syncthreads();
    int d = t & 31, r = t >> 5;
    const float* tzp = ws_t;
    const float* tgp = ws_t + IN_DIM * LD;
    const float* tdp = ws_t + 2 * IN_DIM * LD;
    float a1 = 0.f, a2 = 0.f, ag = 0.f, ad = 0.f;
    #pragma unroll 8
    for (int k = 0; k < IN_DIM; ++k) {
        float tzv = tzp[k * LD + d];
        float tgv = tgp[k * LD + d];
        float tdv = tdp[k * LD + d];
        a1 += sZ[0][r][k] * tzv;
        a2 += sZ[1][r][k] * tzv;
        ag += sZ[2][r][k] * tgv;
        ad += sZ[3][r][k] * tdv;
    }
    long long i = row0 + r;
    dec_out[i * LD + d] = a1;
    dec_out[(long long)N * LD + i * LD + d] = a2;
    dec_out[2LL * N * LD + i * LD + d] = ag;
    dec_out[3LL * N * LD + i * LD + d] = ad;
    float wg = p_wg[0], wd = p_wd[0];
    float w = wg * (ag + 1e-16f) + wd * (ad + 1e-16f);
    // ---- pre-split panels (same arithmetic as the old in-kernel split3)
    float wsc = NE * w;
    int idx = (int)i * LD + d;
    split3s(2.0f * wsc * a1, &pan[idx],           &pan[NP + idx],     &pan[2 * NP + idx]);   // P
    split3s(-wsc,            &pan[3 * NP + idx],  &pan[4 * NP + idx], &pan[5 * NP + idx]);   // Q
    split3s(a2,              &pan[6 * NP + idx],  &pan[7 * NP + idx], &pan[8 * NP + idx]);   // y
    split3s(a2 * a2,         &pan[9 * NP + idx],  &pan[10 * NP + idx],&pan[11 * NP + idx]);  // y^2
    // ---- per-row constant
    float ct = w * a1 * a1;
    ct += __shfl_xor(ct, 1);
    ct += __shfl_xor(ct, 2);
    ct += __shfl_xor(ct, 4);
    ct += __shfl_xor(ct, 8);
    ct += __shfl_xor(ct, 16);
    if (d == 0) ws_c[i] = p_bias[0] - NE * ct;
}

// ---------------- Kernel C: MFMA rank-64 distance GEMM + sigmoid -----------
// logit[i,j] = c[i] + P_i·y_j + Q_i·y2_j, bf16x3, 6 products per half.
// MFMA operands SWAPPED (col-frag first) -> acc holds D^T: lane lr owns row
// rt*16+lr, cols ct*16+4g+reg -> float4 stores. XCD-chunked block swizzle:
// 8 chunks of 16x32 blocks; per-XCD panel footprint ~2.3 MB < 4 MB L2.
__global__ __launch_bounds__(256, 3) void dist_mfma_k(
        const u16* __restrict__ pan,
        const float* __restrict__ ws_c,
        float* __restrict__ out) {
    const u16* Ph = pan;
    const u16* Pm = pan + 1 * NP;
    const u16* Pl = pan + 2 * NP;
    const u16* Qh = pan + 3 * NP;
    const u16* Qm = pan + 4 * NP;
    const u16* Ql = pan + 5 * NP;
    const u16* Yh = pan + 6 * NP;
    const u16* Ym = pan + 7 * NP;
    const u16* Yl = pan + 8 * NP;
    const u16* Wh = pan + 9 * NP;
    const u16* Wm = pan + 10 * NP;
    const u16* Wl = pan + 11 * NP;

    // ---- bijective XCD-chunked swizzle: 4096 blocks -> 8 chunks of 16x32
    int bid = blockIdx.x;
    int xcd = bid & 7, idx = bid >> 3;
    int cr = xcd >> 1, cc = xcd & 1;          // 4x2 chunk grid
    int by = cr * 16 + (idx >> 5);
    int bx = cc * 32 + (idx & 31);

    int t = threadIdx.x;
    int l = t & 63, w = t >> 6;
    int row0 = by * 128 + (w >> 1) * 64;
    int col0 = bx * 128 + (w & 1) * 64;
    int lr = l & 15, g = l >> 4;

    int ao[4], bo[4];
    #pragma unroll
    for (int rt = 0; rt < 4; ++rt) {
        ao[rt] = (row0 + rt * 16 + lr) * LD + 8 * g;
        bo[rt] = (col0 + rt * 16 + lr) * LD + 8 * g;
    }

    v4f acc[16];
    #pragma unroll
    for (int i = 0; i < 16; ++i) acc[i] = (v4f){0.f, 0.f, 0.f, 0.f};

    v8s A0[4], A1[4], A2[4], B0[4], B1[4], B2[4];

    // col-fragment FIRST -> acc = D^T (same products, same order, bit-identical)
    #define DO_PRODUCT(AS, BS)                                              \
        _Pragma("unroll")                                                   \
        for (int rt = 0; rt < 4; ++rt)                                      \
            _Pragma("unroll")                                               \
            for (int ct = 0; ct < 4; ++ct)                                  \
                acc[rt * 4 + ct] = __builtin_amdgcn_mfma_f32_16x16x32_bf16( \
                    BS[ct], AS[rt], acc[rt * 4 + ct], 0, 0, 0);

    // ---- half 1: P · y
    #pragma unroll
    for (int rt = 0; rt < 4; ++rt) {
        A0[rt] = *(const v8s*)(Ph + ao[rt]);
        A1[rt] = *(const v8s*)(Pm + ao[rt]);
    }
    #pragma unroll
    for (int ct = 0; ct < 4; ++ct) {
        B0[ct] = *(const v8s*)(Yh + bo[ct]);
        B1[ct] = *(const v8s*)(Ym + bo[ct]);
    }
    DO_PRODUCT(A0, B0)
    DO_PRODUCT(A0, B1)
    DO_PRODUCT(A1, B0)
    DO_PRODUCT(A1, B1)
    #pragma unroll
    for (int ct = 0; ct < 4; ++ct) B2[ct] = *(const v8s*)(Yl + bo[ct]);
    DO_PRODUCT(A0, B2)
    #pragma unroll
    for (int rt = 0; rt < 4; ++rt) A2[rt] = *(const v8s*)(Pl + ao[rt]);
    DO_PRODUCT(A2, B0)

    // ---- half 2: Q · y^2
    #pragma unroll
    for (int rt = 0; rt < 4; ++rt) {
        A0[rt] = *(const v8s*)(Qh + ao[rt]);
        A1[rt] = *(const v8s*)(Qm + ao[rt]);
    }
    #pragma unroll
    for (int ct = 0; ct < 4; ++ct) {
        B0[ct] = *(const v8s*)(Wh + bo[ct]);
        B1[ct] = *(const v8s*)(Wm + bo[ct]);
    }
    DO_PRODUCT(A0, B0)
    DO_PRODUCT(A0, B1)
    DO_PRODUCT(A1, B0)
    DO_PRODUCT(A1, B1)
    #pragma unroll
    for (int ct = 0; ct < 4; ++ct) B2[ct] = *(const v8s*)(Wl + bo[ct]);
    DO_PRODUCT(A0, B2)
    #pragma unroll
    for (int rt = 0; rt < 4; ++rt) A2[rt] = *(const v8s*)(Ql + ao[rt]);
    DO_PRODUCT(A2, B0)

    // ---- epilogue: add c[i], sigmoid, float4 store
    // D^T layout: lane lr = row rt*16+lr; reg r = col ct*16 + 4g + r
    #pragma unroll
    for (int rt = 0; rt < 4; ++rt) {
        float cv = ws_c[row0 + rt * 16 + lr];
        long long rbase = (long long)(row0 + rt * 16 + lr) * N + col0;
        #pragma unroll
        for (int ct = 0; ct < 4; ++ct) {
            v4f res;
            #pragma unroll
            for (int r = 0; r < 4; ++r) {
                float x = acc[rt * 4 + ct][r] + cv;
                float e = __expf(-x);
                res[r] = __builtin_amdgcn_rcpf(1.0f + e);
            }
            *(v4f*)&out[rbase + ct * 16 + 4 * g] = res;
        }
    }
    #undef DO_PRODUCT
}

extern "C" void kernel_launch(void* const* d_in, const int* in_sizes, int n_in,
                              void* d_out, int out_size, void* d_ws, size_t ws_size,
                              hipStream_t stream) {
    const float* z1    = (const float*)d_in[0];
    const float* gamma = (const float*)d_in[1];
    const float* z2    = (const float*)d_in[2];
    const float* delta = (const float*)d_in[3];
    const float* tz    = (const float*)d_in[4];
    const float* tg    = (const float*)d_in[5];
    const float* td    = (const float*)d_in[6];
    const float* bias  = (const float*)d_in[7];
    const float* wgp   = (const float*)d_in[8];
    const float* wdp   = (const float*)d_in[9];
    float* out = (float*)d_out;
    float* dec_out = out + (long long)N * N;        // z_dec1|z_dec2|gam_dec|del_dec
    float* ws_t = (float*)d_ws;                     // 3*128*32 floats (48 KB)
    float* ws_c = ws_t + 3 * IN_DIM * LD;           // N floats (32 KB)
    u16*   pan  = (u16*)((char*)d_ws + 81920);      // 12 bf16 panels, 6 MB

    softmax_cols_k<<<dim3(3), dim3(256), 0, stream>>>(tz, tg, td, ws_t);
    decode_k<<<dim3(N / ROWS_B), dim3(256), 0, stream>>>(
        z1, gamma, z2, delta, ws_t, bias, wgp, wdp, dec_out, ws_c, pan);
    dist_mfma_k<<<dim3(4096), dim3(256), 0, stream>>>(pan, ws_c, out);
}

// Round 12
// 100.281 us; speedup vs baseline: 1.0539x; 1.0539x over previous
//
#include <hip/hip_runtime.h>

#define N 8192
#define IN_DIM 128
#define LD 32
#define NE 100000.0f
#define NP (N * LD)

typedef float v4f __attribute__((ext_vector_type(4)));
typedef short v8s __attribute__((ext_vector_type(8)));   // 8 bf16 (4 VGPRs)
typedef unsigned int u32;
typedef unsigned short u16;

// ---------------- Kernel A: column softmax (axis=0) of the 3 transforms ----
__global__ __launch_bounds__(256) void softmax_cols_k(
        const float* __restrict__ tz, const float* __restrict__ tg,
        const float* __restrict__ td, float* __restrict__ ws_t) {
    int b = blockIdx.x;
    const float* src = (b == 0) ? tz : (b == 1) ? tg : td;
    float* dst = ws_t + b * (IN_DIM * LD);
    int col = threadIdx.x >> 3, sub = threadIdx.x & 7;   // 32 cols x 8 subs
    float mx = -1e30f;
    #pragma unroll
    for (int j = 0; j < 16; ++j) mx = fmaxf(mx, src[(sub + 8 * j) * LD + col]);
    mx = fmaxf(mx, __shfl_xor(mx, 1));
    mx = fmaxf(mx, __shfl_xor(mx, 2));
    mx = fmaxf(mx, __shfl_xor(mx, 4));
    float s = 0.0f;
    #pragma unroll
    for (int j = 0; j < 16; ++j) s += __expf(src[(sub + 8 * j) * LD + col] - mx);
    s += __shfl_xor(s, 1);
    s += __shfl_xor(s, 2);
    s += __shfl_xor(s, 4);
    float inv = 1.0f / s;
    #pragma unroll
    for (int j = 0; j < 16; ++j)
        dst[(sub + 8 * j) * LD + col] = __expf(src[(sub + 8 * j) * LD + col] - mx) * inv;
}

// exact 3-way bf16 split (truncation): x = h + m + l, drop < 2^-24 rel
__device__ __forceinline__ void split3s(float x, u16* h, u16* m, u16* l) {
    u32 bh = __float_as_uint(x) & 0xFFFF0000u;
    float r = x - __uint_as_float(bh);          // exact
    u32 bm = __float_as_uint(r) & 0xFFFF0000u;
    float s = r - __uint_as_float(bm);          // exact
    *h = (u16)(bh >> 16);
    *m = (u16)(bm >> 16);
    *l = (u16)(__float_as_uint(s) >> 16);
}

// ---------------- Kernel B: decode GEMMs + c[i] + pre-split bf16 panels ----
#define ROWS_B 8
__global__ __launch_bounds__(256) void decode_k(
        const float* __restrict__ z1, const float* __restrict__ gamma,
        const float* __restrict__ z2, const float* __restrict__ delta,
        const float* __restrict__ ws_t,
        const float* __restrict__ p_bias, const float* __restrict__ p_wg,
        const float* __restrict__ p_wd,
        float* __restrict__ dec_out,   // d_out + N*N: z_dec1|z_dec2|gam|del
        float* __restrict__ ws_c,
        u16* __restrict__ pan) {       // 12 panels of [N][LD] bf16
    __shared__ float sZ[4][ROWS_B][IN_DIM];   // 16 KB
    int t = threadIdx.x;
    int row0 = blockIdx.x * ROWS_B;
    for (int i = t; i < 4 * ROWS_B * IN_DIM; i += 256) {
        int a = i >> 10;
        int rr = (i >> 7) & (ROWS_B - 1);
        int k = i & (IN_DIM - 1);
        const float* src = (a == 0) ? z1 : (a == 1) ? z2 : (a == 2) ? gamma : delta;
        (&sZ[0][0][0])[i] = src[(long long)(row0 + rr) * IN_DIM + k];
    }
    __syncthreads();
    int d = t & 31, r = t >> 5;
    const float* tzp = ws_t;
    const float* tgp = ws_t + IN_DIM * LD;
    const float* tdp = ws_t + 2 * IN_DIM * LD;
    float a1 = 0.f, a2 = 0.f, ag = 0.f, ad = 0.f;
    #pragma unroll 8
    for (int k = 0; k < IN_DIM; ++k) {
        float tzv = tzp[k * LD + d];
        float tgv = tgp[k * LD + d];
        float tdv = tdp[k * LD + d];
        a1 += sZ[0][r][k] * tzv;
        a2 += sZ[1][r][k] * tzv;
        ag += sZ[2][r][k] * tgv;
        ad += sZ[3][r][k] * tdv;
    }
    long long i = row0 + r;
    dec_out[i * LD + d] = a1;
    dec_out[(long long)N * LD + i * LD + d] = a2;
    dec_out[2LL * N * LD + i * LD + d] = ag;
    dec_out[3LL * N * LD + i * LD + d] = ad;
    float wg = p_wg[0], wd = p_wd[0];
    float w = wg * (ag + 1e-16f) + wd * (ad + 1e-16f);
    // ---- pre-split panels
    float wsc = NE * w;
    int idx = (int)i * LD + d;
    split3s(2.0f * wsc * a1, &pan[idx],           &pan[NP + idx],     &pan[2 * NP + idx]);   // P
    split3s(-wsc,            &pan[3 * NP + idx],  &pan[4 * NP + idx], &pan[5 * NP + idx]);   // Q
    split3s(a2,              &pan[6 * NP + idx],  &pan[7 * NP + idx], &pan[8 * NP + idx]);   // y
    split3s(a2 * a2,         &pan[9 * NP + idx],  &pan[10 * NP + idx],&pan[11 * NP + idx]);  // y^2
    // ---- per-row constant
    float ct = w * a1 * a1;
    ct += __shfl_xor(ct, 1);
    ct += __shfl_xor(ct, 2);
    ct += __shfl_xor(ct, 4);
    ct += __shfl_xor(ct, 8);
    ct += __shfl_xor(ct, 16);
    if (d == 0) ws_c[i] = p_bias[0] - NE * ct;
}

// ---------------- Kernel C: MFMA rank-64 distance GEMM + sigmoid -----------
// logit[i,j] = c[i] + P_i·y_j + Q_i·y2_j, bf16x3, 6 products per half.
// Main loop unchanged from round 11 (bit-identical). NEW: epilogue stages the
// 128x128 block tile through LDS (chunk-XOR swizzle) so global stores are
// contiguous 512B row segments, sequential rows; nontemporal to keep the
// 268 MB stream from evicting L2-resident panels. (256,2): no spills.
__global__ __launch_bounds__(256, 2) void dist_mfma_k(
        const u16* __restrict__ pan,
        const float* __restrict__ ws_c,
        float* __restrict__ out) {
    __shared__ float lds[128 * 128];   // 64 KB epilogue transpose buffer
    const u16* Ph = pan;
    const u16* Pm = pan + 1 * NP;
    const u16* Pl = pan + 2 * NP;
    const u16* Qh = pan + 3 * NP;
    const u16* Qm = pan + 4 * NP;
    const u16* Ql = pan + 5 * NP;
    const u16* Yh = pan + 6 * NP;
    const u16* Ym = pan + 7 * NP;
    const u16* Yl = pan + 8 * NP;
    const u16* Wh = pan + 9 * NP;
    const u16* Wm = pan + 10 * NP;
    const u16* Wl = pan + 11 * NP;

    // ---- bijective XCD-chunked swizzle: 4096 blocks -> 8 chunks of 16x32
    int bid = blockIdx.x;
    int xcd = bid & 7, idx = bid >> 3;
    int cr = xcd >> 1, cc = xcd & 1;          // 4x2 chunk grid
    int by = cr * 16 + (idx >> 5);
    int bx = cc * 32 + (idx & 31);

    int t = threadIdx.x;
    int l = t & 63, w = t >> 6;
    int row0b = by * 128, col0b = bx * 128;
    int lrow_w = (w >> 1) * 64, lcol_w = (w & 1) * 64;
    int row0 = row0b + lrow_w;
    int col0 = col0b + lcol_w;
    int lr = l & 15, g = l >> 4;

    int ao[4], bo[4];
    #pragma unroll
    for (int rt = 0; rt < 4; ++rt) {
        ao[rt] = (row0 + rt * 16 + lr) * LD + 8 * g;
        bo[rt] = (col0 + rt * 16 + lr) * LD + 8 * g;
    }

    v4f acc[16];
    #pragma unroll
    for (int i = 0; i < 16; ++i) acc[i] = (v4f){0.f, 0.f, 0.f, 0.f};

    v8s A0[4], A1[4], A2[4], B0[4], B1[4], B2[4];

    // col-fragment FIRST -> acc = D^T (row = lr, col = 4g+reg within tiles)
    #define DO_PRODUCT(AS, BS)                                              \
        _Pragma("unroll")                                                   \
        for (int rt = 0; rt < 4; ++rt)                                      \
            _Pragma("unroll")                                               \
            for (int ct = 0; ct < 4; ++ct)                                  \
                acc[rt * 4 + ct] = __builtin_amdgcn_mfma_f32_16x16x32_bf16( \
                    BS[ct], AS[rt], acc[rt * 4 + ct], 0, 0, 0);

    // ---- half 1: P · y
    #pragma unroll
    for (int rt = 0; rt < 4; ++rt) {
        A0[rt] = *(const v8s*)(Ph + ao[rt]);
        A1[rt] = *(const v8s*)(Pm + ao[rt]);
    }
    #pragma unroll
    for (int ct = 0; ct < 4; ++ct) {
        B0[ct] = *(const v8s*)(Yh + bo[ct]);
        B1[ct] = *(const v8s*)(Ym + bo[ct]);
    }
    DO_PRODUCT(A0, B0)
    DO_PRODUCT(A0, B1)
    DO_PRODUCT(A1, B0)
    DO_PRODUCT(A1, B1)
    #pragma unroll
    for (int ct = 0; ct < 4; ++ct) B2[ct] = *(const v8s*)(Yl + bo[ct]);
    DO_PRODUCT(A0, B2)
    #pragma unroll
    for (int rt = 0; rt < 4; ++rt) A2[rt] = *(const v8s*)(Pl + ao[rt]);
    DO_PRODUCT(A2, B0)

    // ---- half 2: Q · y^2
    #pragma unroll
    for (int rt = 0; rt < 4; ++rt) {
        A0[rt] = *(const v8s*)(Qh + ao[rt]);
        A1[rt] = *(const v8s*)(Qm + ao[rt]);
    }
    #pragma unroll
    for (int ct = 0; ct < 4; ++ct) {
        B0[ct] = *(const v8s*)(Wh + bo[ct]);
        B1[ct] = *(const v8s*)(Wm + bo[ct]);
    }
    DO_PRODUCT(A0, B0)
    DO_PRODUCT(A0, B1)
    DO_PRODUCT(A1, B0)
    DO_PRODUCT(A1, B1)
    #pragma unroll
    for (int ct = 0; ct < 4; ++ct) B2[ct] = *(const v8s*)(Wl + bo[ct]);
    DO_PRODUCT(A0, B2)
    #pragma unroll
    for (int rt = 0; rt < 4; ++rt) A2[rt] = *(const v8s*)(Ql + ao[rt]);
    DO_PRODUCT(A2, B0)

    // ---- epilogue phase 1: add c[i], stage to LDS (chunk-XOR swizzled)
    #pragma unroll
    for (int rt = 0; rt < 4; ++rt) {
        int lrow = lrow_w + rt * 16 + lr;            // 0..127 in block
        float cv = ws_c[row0b + lrow];
        #pragma unroll
        for (int ct = 0; ct < 4; ++ct) {
            v4f v = acc[rt * 4 + ct];
            #pragma unroll
            for (int r = 0; r < 4; ++r) v[r] += cv;
            int chunk = (lcol_w + ct * 16 + g * 4) >> 2;          // 0..31
            int dw = lrow * 128 + ((chunk ^ (lrow & 7)) << 2);
            *(v4f*)&lds[dw] = v;
        }
    }
    __syncthreads();

    // ---- epilogue phase 2: sigmoid + contiguous row stores (512B segments)
    #pragma unroll
    for (int i = 0; i < 16; ++i) {
        int lrow = w * 32 + 2 * i + (l >> 5);        // 0..127
        int chunk = l & 31;
        int dw = lrow * 128 + ((chunk ^ (lrow & 7)) << 2);
        v4f v = *(const v4f*)&lds[dw];
        v4f res;
        #pragma unroll
        for (int r = 0; r < 4; ++r) {
            float e = __expf(-v[r]);
            res[r] = __builtin_amdgcn_rcpf(1.0f + e);
        }
        long long addr = (long long)(row0b + lrow) * N + col0b + chunk * 4;
        __builtin_nontemporal_store(res, (v4f*)&out[addr]);
    }
    #undef DO_PRODUCT
}

extern "C" void kernel_launch(void* const* d_in, const int* in_sizes, int n_in,
                              void* d_out, int out_size, void* d_ws, size_t ws_size,
                              hipStream_t stream) {
    const float* z1    = (const float*)d_in[0];
    const float* gamma = (const float*)d_in[1];
    const float* z2    = (const float*)d_in[2];
    const float* delta = (const float*)d_in[3];
    const float* tz    = (const float*)d_in[4];
    const float* tg    = (const float*)d_in[5];
    const float* td    = (const float*)d_in[6];
    const float* bias  = (const float*)d_in[7];
    const float* wgp   = (const float*)d_in[8];
    const float* wdp   = (const float*)d_in[9];
    float* out = (float*)d_out;
    float* dec_out = out + (long long)N * N;        // z_dec1|z_dec2|gam_dec|del_dec
    float* ws_t = (float*)d_ws;                     // 3*128*32 floats (48 KB)
    float* ws_c = ws_t + 3 * IN_DIM * LD;           // N floats (32 KB)
    u16*   pan  = (u16*)((char*)d_ws + 81920);      // 12 bf16 panels, 6 MB

    softmax_cols_k<<<dim3(3), dim3(256), 0, stream>>>(tz, tg, td, ws_t);
    decode_k<<<dim3(N / ROWS_B), dim3(256), 0, stream>>>(
        z1, gamma, z2, delta, ws_t, bias, wgp, wdp, dec_out, ws_c, pan);
    dist_mfma_k<<<dim3(4096), dim3(256), 0, stream>>>(pan, ws_c, out);
}